// Round 2
// 350.330 us; speedup vs baseline: 1.0400x; 1.0400x over previous
//
#include <hip/hip_runtime.h>

#define NS 4096
#define IND 768
#define PP 64
#define DD 256
#define EPSF 1e-8f
#define KHALF 384

typedef float f32x4 __attribute__((ext_vector_type(4)));

// ==== kernel 1: fused z-GEMM (blocks 0..511) + prototype prep (blocks 512..575) ====
// GEMM: 64x64 tile, split-K=2, 4x4/thread, single-LDS-buffer + register prefetch.
// Proto blocks: pnorm, pairwise-distance row sums, scalar-accumulator init.
__global__ __launch_bounds__(256) void k_pre(const float* __restrict__ x,
                                             const float* __restrict__ W,
                                             const float* __restrict__ protos,
                                             float* __restrict__ z0,
                                             float* __restrict__ z1,
                                             float* __restrict__ pnorm,
                                             float* __restrict__ ppsum,
                                             unsigned int* __restrict__ minu,
                                             float* __restrict__ accum) {
    __shared__ float As[16][68];
    __shared__ float Bs[16][68];
    int tid = threadIdx.x;
    int bid = blockIdx.x;

    if (bid >= 512) {
        // ---------------- prototype path ----------------
        int p = bid - 512;
        int lane = tid & 63, w = tid >> 6;
        if (w == 0) {
            float s = 0.f;
            for (int d = lane; d < DD; d += 64) { float v = protos[p * DD + d]; s += v * v; }
#pragma unroll
            for (int o = 1; o < 64; o <<= 1) s += __shfl_xor(s, o);
            if (lane == 0) pnorm[p] = sqrtf(s);
        }
        // pairwise distance: thread = (q, quarter of D)
        int q = tid >> 2, quarter = tid & 3;
        const float* pr = protos + p * DD + quarter * 64;
        const float* qr = protos + q * DD + quarter * 64;
        float s2 = 0.f;
        for (int d = 0; d < 64; ++d) { float diff = pr[d] - qr[d]; s2 += diff * diff; }
        s2 += __shfl_xor(s2, 1);
        s2 += __shfl_xor(s2, 2);
        float contrib = (quarter == 0 && q != p) ? sqrtf(s2) : 0.f;
#pragma unroll
        for (int o = 1; o < 64; o <<= 1) contrib += __shfl_xor(contrib, o);
        float* red = &As[0][0];
        if (lane == 0) red[w] = contrib;
        __syncthreads();
        if (tid == 0) {
            ppsum[p] = red[0] + red[1] + red[2] + red[3];
            minu[p] = 0xFFFFFFFFu;                 // uint-max == +inf for float-bits atomicMin
            if (p == 0) {
                accum[0] = 0.f; accum[1] = 0.f; accum[2] = 0.f;
                ((unsigned int*)accum)[3] = 0u;    // block-completion ticket for k_cosw
            }
        }
        return;
    }

    // ---------------- GEMM path ----------------
    int bx = bid & 63, by = (bid >> 6) & 3, bz = bid >> 8;
    int m0 = bx * 64, n0 = by * 64, kbase = bz * KHALF;
    float* __restrict__ zout = bz ? z1 : z0;
    float c[4][4] = {};
    int tx = tid & 15, ty = tid >> 4;
    int ka = tid & 15, mb = tid >> 4;   // As staging coords
    int nb = tid & 63, kb = tid >> 6;   // Bs staging coords
    const float* xp = x + (size_t)(m0 + mb) * IND + kbase + ka;
    const float* wp = W + (size_t)(kbase + kb) * DD + n0 + nb;

    float ra[4], rb[4];
#pragma unroll
    for (int r = 0; r < 4; ++r) ra[r] = xp[r * 16 * IND];
#pragma unroll
    for (int r = 0; r < 4; ++r) rb[r] = wp[(size_t)(r * 4) * DD];

    for (int k0 = 0; k0 < KHALF; k0 += 16) {
#pragma unroll
        for (int r = 0; r < 4; ++r) As[ka][mb + r * 16] = ra[r];
#pragma unroll
        for (int r = 0; r < 4; ++r) Bs[kb + r * 4][nb] = rb[r];
        __syncthreads();
        if (k0 + 16 < KHALF) {  // prefetch next slab under the FMA block
#pragma unroll
            for (int r = 0; r < 4; ++r) ra[r] = xp[k0 + 16 + r * 16 * IND];
#pragma unroll
            for (int r = 0; r < 4; ++r) rb[r] = wp[(size_t)(k0 + 16 + r * 4) * DD];
        }
#pragma unroll
        for (int k = 0; k < 16; ++k) {
            float a[4], bb[4];
#pragma unroll
            for (int i = 0; i < 4; ++i) a[i] = As[k][ty * 4 + i];
#pragma unroll
            for (int j = 0; j < 4; ++j) bb[j] = Bs[k][tx * 4 + j];
#pragma unroll
            for (int i = 0; i < 4; ++i)
#pragma unroll
                for (int j = 0; j < 4; ++j) c[i][j] += a[i] * bb[j];
        }
        __syncthreads();
    }
#pragma unroll
    for (int i = 0; i < 4; ++i) {
        int m = m0 + ty * 4 + i;
#pragma unroll
        for (int j = 0; j < 4; ++j) zout[(size_t)m * DD + n0 + tx * 4 + j] = c[i][j];
    }
}

// ==== kernel 2: z combine + norms + cos/dist + reductions + token write + final ====
// 512 blocks x 256 threads, 8 samples/block (2/wave). LDS ~75 KB -> 2 blocks/CU.
__global__ __launch_bounds__(256) void k_cosw(const float* __restrict__ z0,
                                              const float* __restrict__ z1,
                                              const float* __restrict__ bias,
                                              const float* __restrict__ protos,
                                              const float* __restrict__ pnorm,
                                              const int* __restrict__ labels,
                                              float* __restrict__ out,
                                              unsigned int* __restrict__ minu,
                                              float* __restrict__ accum,
                                              const float* __restrict__ ppsum,
                                              int out_last) {
    __shared__ float protoT[PP * DD];                 // [d*64 + (p ^ (d&31))]
    __shared__ __align__(16) float rowbuf[4][2][DD];  // [wave][sample][d]
    __shared__ float wmin[4][64];
    __shared__ float wacc[4][3];
    int tid = threadIdx.x;
    for (int idx = tid; idx < PP * DD; idx += 256) {
        int p = idx >> 8, d = idx & 255;
        protoT[d * 64 + (p ^ (d & 31))] = protos[idx];
    }

    int w = tid >> 6, lane = tid & 63;
    int p = lane;
    float pn = pnorm[p];
    float pn2 = pn * pn;
    float4 b4 = ((const float4*)bias)[lane];
    int nbase = blockIdx.x * 8 + w * 2;

    float zn[2];
#pragma unroll
    for (int s = 0; s < 2; ++s) {
        int n = nbase + s;
        float4 a = ((const float4*)z0)[n * 64 + lane];
        float4 cc = ((const float4*)z1)[n * 64 + lane];
        float4 r;
        r.x = a.x + cc.x + b4.x; r.y = a.y + cc.y + b4.y;
        r.z = a.z + cc.z + b4.z; r.w = a.w + cc.w + b4.w;
        float ss = r.x * r.x + r.y * r.y + r.z * r.z + r.w * r.w;
#pragma unroll
        for (int o = 1; o < 64; o <<= 1) ss += __shfl_xor(ss, o);
        zn[s] = sqrtf(ss);
        ((float4*)rowbuf[w][s])[lane] = r;
    }
    __syncthreads();  // protoT staging + rowbuf visibility

    float dot0 = 0.f, dot1 = 0.f;
#pragma unroll 8
    for (int d4 = 0; d4 < 64; ++d4) {
        float4 r0 = ((const float4*)rowbuf[w][0])[d4];
        float4 r1 = ((const float4*)rowbuf[w][1])[d4];
        int d = d4 * 4;
        float p0 = protoT[(d + 0) * 64 + (p ^ ((d + 0) & 31))];
        float p1 = protoT[(d + 1) * 64 + (p ^ ((d + 1) & 31))];
        float p2 = protoT[(d + 2) * 64 + (p ^ ((d + 2) & 31))];
        float p3 = protoT[(d + 3) * 64 + (p ^ ((d + 3) & 31))];
        dot0 += r0.x * p0 + r0.y * p1 + r0.z * p2 + r0.w * p3;
        dot1 += r1.x * p0 + r1.y * p1 + r1.z * p2 + r1.w * p3;
    }
    float dots[2] = {dot0, dot1};

    float cosv[2];
    float regmin = 3.4e38f;
    float s_pz = 0.f, s_cl = 0.f, s_num = 0.f;
#pragma unroll
    for (int s = 0; s < 2; ++s) {
        int n = nbase + s;
        float dot = dots[s];
        float c = dot / (fmaxf(zn[s], EPSF) * fmaxf(pn, EPSF));
        cosv[s] = c;
        float d2 = zn[s] * zn[s] + pn2 - 2.f * dot;
        float dist = sqrtf(fmaxf(d2, 0.f));
        regmin = fminf(regmin, dist);

        unsigned long long bal = __ballot(c > 0.5f);
        int cnt = __popcll(bal);

        float mind = dist;
#pragma unroll
        for (int o = 1; o < 64; o <<= 1) mind = fminf(mind, __shfl_xor(mind, o));
        float mx = c;
#pragma unroll
        for (int o = 1; o < 32; o <<= 1) mx = fmaxf(mx, __shfl_xor(mx, o));
        float max_pos = __shfl(mx, 0);
        float max_neg = __shfl(mx, 32);
        if (lane == 0) {
            float dcl = (labels[n] == 1) ? (1.f - max_pos) : (1.f - max_neg);
            s_pz += mind;
            s_cl += dcl;
            if (cnt > 16) s_num += 1.f;
        }
    }

    // ---- block-level reduction, one atomic set per block ----
    wmin[w][lane] = regmin;
    if (lane == 0) { wacc[w][0] = s_pz; wacc[w][1] = s_cl; wacc[w][2] = s_num; }
    __syncthreads();
    if (w == 0) {
        float m = fminf(fminf(wmin[0][lane], wmin[1][lane]),
                        fminf(wmin[2][lane], wmin[3][lane]));
        atomicMin(&minu[lane], __float_as_uint(m));
        if (lane == 0) {
            atomicAdd(&accum[0], wacc[0][0] + wacc[1][0] + wacc[2][0] + wacc[3][0]);
            atomicAdd(&accum[1], wacc[0][1] + wacc[1][1] + wacc[2][1] + wacc[3][1]);
            atomicAdd(&accum[2], wacc[0][2] + wacc[1][2] + wacc[2][2] + wacc[3][2]);
        }
        __threadfence();  // release: this block's atomics globally visible before ticket
        unsigned int t = 0;
        if (lane == 0) t = atomicAdd((unsigned int*)accum + 3, 1u);
        t = __shfl(t, 0);
        if (t == 511u) {  // last block finalizes the scalar loss
            __threadfence();
            // atomic no-op reads: coherent with all blocks' device-scope atomics
            float mv = __uint_as_float(atomicMin(&minu[lane], 0xFFFFFFFFu));
            float v = mv * (1.f / PP) + ppsum[lane] * (1.f / (PP * (PP - 1)));
#pragma unroll
            for (int o = 1; o < 64; o <<= 1) v += __shfl_xor(v, o);
            if (lane == 0) {
                float l_pz = atomicAdd(&accum[0], 0.f) * (1.f / NS);
                float l_cl = atomicAdd(&accum[1], 0.f) * (1.f / NS);
                float l_num = atomicAdd(&accum[2], 0.f);
                out[out_last] = v + l_pz + l_num + 2.f * l_cl;
            }
        }
    }

    // ---- token write: out[n][pp][d] = cos[n][pp] * protos[pp][d], 1KB/instr, NT ----
    const float4* pr4 = (const float4*)protos;
#pragma unroll
    for (int s = 0; s < 2; ++s) {
        int n = nbase + s;
        f32x4* o4 = (f32x4*)out + (size_t)n * 4096 + lane;
        float cv = cosv[s];
#pragma unroll 4
        for (int pp = 0; pp < 64; ++pp) {
            float c = __shfl(cv, pp);
            float4 v = pr4[pp * 64 + lane];
            f32x4 r;
            r.x = c * v.x; r.y = c * v.y; r.z = c * v.z; r.w = c * v.w;
            __builtin_nontemporal_store(r, &o4[pp * 64]);
        }
    }
}

extern "C" void kernel_launch(void* const* d_in, const int* in_sizes, int n_in,
                              void* d_out, int out_size, void* d_ws, size_t ws_size,
                              hipStream_t stream) {
    const float* x      = (const float*)d_in[0];
    const int*   labels = (const int*)d_in[1];
    const float* W      = (const float*)d_in[2];
    const float* bias   = (const float*)d_in[3];
    const float* protos = (const float*)d_in[4];
    float* out = (float*)d_out;
    float* ws = (float*)d_ws;

    float* z0    = ws;                    // 4096*256
    float* z1    = ws + 1048576;          // 4096*256
    float* pnorm = ws + 2097152;          // 64
    float* ppsum = pnorm + 64;            // 64
    unsigned int* minu = (unsigned int*)(ppsum + 64);  // 64
    float* accum = (float*)(minu + 64);   // 3 accumulators + 1 ticket

    k_pre<<<576, 256, 0, stream>>>(x, W, protos, z0, z1, pnorm, ppsum, minu, accum);
    k_cosw<<<512, 256, 0, stream>>>(z0, z1, bias, protos, pnorm, labels, out,
                                    minu, accum, ppsum, out_size - 1);
}

// Round 3
// 342.805 us; speedup vs baseline: 1.0628x; 1.0220x over previous
//
#include <hip/hip_runtime.h>

#define NS 4096
#define IND 768
#define PP 64
#define DD 256
#define EPSF 1e-8f
#define KHALF 384

typedef float f32x4 __attribute__((ext_vector_type(4)));

// ==== kernel 1: fused z-GEMM (blocks 0..511) + prototype prep (blocks 512..575) ====
// GEMM: 64x64 tile, split-K=2, 4x4/thread, single-LDS-buffer + float4 register prefetch.
// Proto blocks: pnorm, pairwise-distance row sums, scalar-accumulator init.
__global__ __launch_bounds__(256) void k_pre(const float* __restrict__ x,
                                             const float* __restrict__ W,
                                             const float* __restrict__ protos,
                                             float* __restrict__ z0,
                                             float* __restrict__ z1,
                                             float* __restrict__ pnorm,
                                             float* __restrict__ ppsum,
                                             unsigned int* __restrict__ minu,
                                             float* __restrict__ accum) {
    __shared__ float As[16][68];
    __shared__ float Bs[16][68];
    int tid = threadIdx.x;
    int bid = blockIdx.x;

    if (bid >= 512) {
        // ---------------- prototype path ----------------
        int p = bid - 512;
        int lane = tid & 63, w = tid >> 6;
        if (w == 0) {
            float s = 0.f;
            for (int d = lane; d < DD; d += 64) { float v = protos[p * DD + d]; s += v * v; }
#pragma unroll
            for (int o = 1; o < 64; o <<= 1) s += __shfl_xor(s, o);
            if (lane == 0) pnorm[p] = sqrtf(s);
        }
        // pairwise distance: thread = (q, quarter of D)
        int q = tid >> 2, quarter = tid & 3;
        const float* pr = protos + p * DD + quarter * 64;
        const float* qr = protos + q * DD + quarter * 64;
        float s2 = 0.f;
        for (int d = 0; d < 64; ++d) { float diff = pr[d] - qr[d]; s2 += diff * diff; }
        s2 += __shfl_xor(s2, 1);
        s2 += __shfl_xor(s2, 2);
        float contrib = (quarter == 0 && q != p) ? sqrtf(s2) : 0.f;
#pragma unroll
        for (int o = 1; o < 64; o <<= 1) contrib += __shfl_xor(contrib, o);
        float* red = &As[0][0];
        if (lane == 0) red[w] = contrib;
        __syncthreads();
        if (tid == 0) {
            ppsum[p] = red[0] + red[1] + red[2] + red[3];
            minu[p] = 0xFFFFFFFFu;                 // uint-max == +inf for float-bits atomicMin
            if (p == 0) {
                accum[0] = 0.f; accum[1] = 0.f; accum[2] = 0.f;
                ((unsigned int*)accum)[3] = 0u;    // block-completion ticket for k_cosw
            }
        }
        return;
    }

    // ---------------- GEMM path ----------------
    int bx = bid & 63, by = (bid >> 6) & 3, bz = bid >> 8;
    int m0 = bx * 64, n0 = by * 64, kbase = bz * KHALF;
    float* __restrict__ zout = bz ? z1 : z0;
    float c[4][4] = {};
    int tx = tid & 15, ty = tid >> 4;
    // A staging: thread loads float4 along K at row (tid>>2), k-quad (tid&3)*4
    int am = tid >> 2, ak = (tid & 3) * 4;
    // B staging: thread loads float4 along N at k-row (tid>>4), n-quad (tid&15)*4
    int bk = tid >> 4, bn = (tid & 15) * 4;
    const float* xp = x + (size_t)(m0 + am) * IND + kbase + ak;
    const float* wp = W + (size_t)(kbase + bk) * DD + n0 + bn;

    f32x4 ra = *(const f32x4*)xp;
    f32x4 rb = *(const f32x4*)wp;

    for (int k0 = 0; k0 < KHALF; k0 += 16) {
        As[ak + 0][am] = ra.x;
        As[ak + 1][am] = ra.y;
        As[ak + 2][am] = ra.z;
        As[ak + 3][am] = ra.w;
        *(f32x4*)&Bs[bk][bn] = rb;
        __syncthreads();
        if (k0 + 16 < KHALF) {  // prefetch next slab under the FMA block
            ra = *(const f32x4*)(xp + k0 + 16);
            rb = *(const f32x4*)(wp + (size_t)(k0 + 16) * DD);
        }
#pragma unroll
        for (int k = 0; k < 16; ++k) {
            float a[4], bb[4];
#pragma unroll
            for (int i = 0; i < 4; ++i) a[i] = As[k][ty * 4 + i];
#pragma unroll
            for (int j = 0; j < 4; ++j) bb[j] = Bs[k][tx * 4 + j];
#pragma unroll
            for (int i = 0; i < 4; ++i)
#pragma unroll
                for (int j = 0; j < 4; ++j) c[i][j] += a[i] * bb[j];
        }
        __syncthreads();
    }
#pragma unroll
    for (int i = 0; i < 4; ++i) {
        int m = m0 + ty * 4 + i;
#pragma unroll
        for (int j = 0; j < 4; ++j) zout[(size_t)m * DD + n0 + tx * 4 + j] = c[i][j];
    }
}

// ==== kernel 2: z combine + norms + cos/dist + token write + reductions + final ====
// 512 blocks x 256 threads, 8 samples/block (2/wave). LDS ~73 KB -> 2 blocks/CU.
__global__ __launch_bounds__(256) void k_cosw(const float* __restrict__ z0,
                                              const float* __restrict__ z1,
                                              const float* __restrict__ bias,
                                              const float* __restrict__ protos,
                                              const float* __restrict__ pnorm,
                                              const int* __restrict__ labels,
                                              float* __restrict__ out,
                                              unsigned int* __restrict__ minu,
                                              float* __restrict__ accum,
                                              const float* __restrict__ ppsum,
                                              int out_last) {
    __shared__ float protoT[PP * DD];                 // [d*64 + (p ^ (d&31))]
    __shared__ __align__(16) float rowbuf[4][2][DD];  // [wave][sample][d]
    __shared__ float wmin[4][64];
    __shared__ float wacc[4][3];
    int tid = threadIdx.x;
    for (int idx = tid; idx < PP * DD; idx += 256) {
        int p = idx >> 8, d = idx & 255;
        protoT[d * 64 + (p ^ (d & 31))] = protos[idx];
    }

    int w = tid >> 6, lane = tid & 63;
    int p = lane;
    float pn = pnorm[p];
    float pn2 = pn * pn;
    float4 b4 = ((const float4*)bias)[lane];
    int nbase = blockIdx.x * 8 + w * 2;

    float zn[2];
#pragma unroll
    for (int s = 0; s < 2; ++s) {
        int n = nbase + s;
        float4 a = ((const float4*)z0)[n * 64 + lane];
        float4 cc = ((const float4*)z1)[n * 64 + lane];
        float4 r;
        r.x = a.x + cc.x + b4.x; r.y = a.y + cc.y + b4.y;
        r.z = a.z + cc.z + b4.z; r.w = a.w + cc.w + b4.w;
        float ss = r.x * r.x + r.y * r.y + r.z * r.z + r.w * r.w;
#pragma unroll
        for (int o = 1; o < 64; o <<= 1) ss += __shfl_xor(ss, o);
        zn[s] = sqrtf(ss);
        ((float4*)rowbuf[w][s])[lane] = r;
    }
    __syncthreads();  // protoT staging + rowbuf visibility

    float dot0 = 0.f, dot1 = 0.f;
#pragma unroll 8
    for (int d4 = 0; d4 < 64; ++d4) {
        float4 r0 = ((const float4*)rowbuf[w][0])[d4];
        float4 r1 = ((const float4*)rowbuf[w][1])[d4];
        int d = d4 * 4;
        float p0 = protoT[(d + 0) * 64 + (p ^ ((d + 0) & 31))];
        float p1 = protoT[(d + 1) * 64 + (p ^ ((d + 1) & 31))];
        float p2 = protoT[(d + 2) * 64 + (p ^ ((d + 2) & 31))];
        float p3 = protoT[(d + 3) * 64 + (p ^ ((d + 3) & 31))];
        dot0 += r0.x * p0 + r0.y * p1 + r0.z * p2 + r0.w * p3;
        dot1 += r1.x * p0 + r1.y * p1 + r1.z * p2 + r1.w * p3;
    }
    float dots[2] = {dot0, dot1};

    float cosv[2];
    float regmin = 3.4e38f;
    float s_pz = 0.f, s_cl = 0.f, s_num = 0.f;
#pragma unroll
    for (int s = 0; s < 2; ++s) {
        int n = nbase + s;
        float dot = dots[s];
        float c = dot / (fmaxf(zn[s], EPSF) * fmaxf(pn, EPSF));
        cosv[s] = c;
        float d2 = zn[s] * zn[s] + pn2 - 2.f * dot;
        float dist = sqrtf(fmaxf(d2, 0.f));
        regmin = fminf(regmin, dist);

        unsigned long long bal = __ballot(c > 0.5f);
        int cnt = __popcll(bal);

        float mind = dist;
#pragma unroll
        for (int o = 1; o < 64; o <<= 1) mind = fminf(mind, __shfl_xor(mind, o));
        float mx = c;
#pragma unroll
        for (int o = 1; o < 32; o <<= 1) mx = fmaxf(mx, __shfl_xor(mx, o));
        float max_pos = __shfl(mx, 0);
        float max_neg = __shfl(mx, 32);
        if (lane == 0) {
            float dcl = (labels[n] == 1) ? (1.f - max_pos) : (1.f - max_neg);
            s_pz += mind;
            s_cl += dcl;
            if (cnt > 16) s_num += 1.f;
        }
    }

    // ---- token write FIRST: get the NT store stream going immediately ----
    // out[n][pp][d] = cos[n][pp] * protos[pp][d]; one proto load serves both samples.
    {
        const f32x4* pr4 = (const f32x4*)protos;
        f32x4* o0 = (f32x4*)out + (size_t)(nbase + 0) * 4096 + lane;
        f32x4* o1 = (f32x4*)out + (size_t)(nbase + 1) * 4096 + lane;
        float cv0 = cosv[0], cv1 = cosv[1];
#pragma unroll 8
        for (int pp = 0; pp < 64; ++pp) {
            f32x4 v = pr4[pp * 64 + lane];
            float c0 = __shfl(cv0, pp);
            float c1 = __shfl(cv1, pp);
            __builtin_nontemporal_store(c0 * v, &o0[pp * 64]);
            __builtin_nontemporal_store(c1 * v, &o1[pp * 64]);
        }
    }

    // ---- block-level reduction, one atomic set per block, then last-block finalize ----
    wmin[w][lane] = regmin;
    if (lane == 0) { wacc[w][0] = s_pz; wacc[w][1] = s_cl; wacc[w][2] = s_num; }
    __syncthreads();
    if (w == 0) {
        float m = fminf(fminf(wmin[0][lane], wmin[1][lane]),
                        fminf(wmin[2][lane], wmin[3][lane]));
        atomicMin(&minu[lane], __float_as_uint(m));
        if (lane == 0) {
            atomicAdd(&accum[0], wacc[0][0] + wacc[1][0] + wacc[2][0] + wacc[3][0]);
            atomicAdd(&accum[1], wacc[0][1] + wacc[1][1] + wacc[2][1] + wacc[3][1]);
            atomicAdd(&accum[2], wacc[0][2] + wacc[1][2] + wacc[2][2] + wacc[3][2]);
        }
        __threadfence();  // release: this block's atomics globally visible before ticket
        unsigned int t = 0;
        if (lane == 0) t = atomicAdd((unsigned int*)accum + 3, 1u);
        t = __shfl(t, 0);
        if (t == 511u) {  // last block finalizes the scalar loss
            __threadfence();
            // atomic no-op reads: coherent with all blocks' device-scope atomics
            float mv = __uint_as_float(atomicMin(&minu[lane], 0xFFFFFFFFu));
            float v = mv * (1.f / PP) + ppsum[lane] * (1.f / (PP * (PP - 1)));
#pragma unroll
            for (int o = 1; o < 64; o <<= 1) v += __shfl_xor(v, o);
            if (lane == 0) {
                float l_pz = atomicAdd(&accum[0], 0.f) * (1.f / NS);
                float l_cl = atomicAdd(&accum[1], 0.f) * (1.f / NS);
                float l_num = atomicAdd(&accum[2], 0.f);
                out[out_last] = v + l_pz + l_num + 2.f * l_cl;
            }
        }
    }
}

extern "C" void kernel_launch(void* const* d_in, const int* in_sizes, int n_in,
                              void* d_out, int out_size, void* d_ws, size_t ws_size,
                              hipStream_t stream) {
    const float* x      = (const float*)d_in[0];
    const int*   labels = (const int*)d_in[1];
    const float* W      = (const float*)d_in[2];
    const float* bias   = (const float*)d_in[3];
    const float* protos = (const float*)d_in[4];
    float* out = (float*)d_out;
    float* ws = (float*)d_ws;

    float* z0    = ws;                    // 4096*256
    float* z1    = ws + 1048576;          // 4096*256
    float* pnorm = ws + 2097152;          // 64
    float* ppsum = pnorm + 64;            // 64
    unsigned int* minu = (unsigned int*)(ppsum + 64);  // 64
    float* accum = (float*)(minu + 64);   // 3 accumulators + 1 ticket

    k_pre<<<576, 256, 0, stream>>>(x, W, protos, z0, z1, pnorm, ppsum, minu, accum);
    k_cosw<<<512, 256, 0, stream>>>(z0, z1, bias, protos, pnorm, labels, out,
                                    minu, accum, ppsum, out_size - 1);
}